// Round 1
// baseline (1139.925 us; speedup 1.0000x reference)
//
#include <hip/hip_runtime.h>

// VectorQuantizer: x [16,4096,256] f32, embedding [1024,256] f32
// outputs (concat): quantized_st [16,4096,256] f32, loss f32, perplexity f32
//
// M = 65536 rows, N = 1024 codes, E = 256 dims.
//
// ws layout:
//   idx      : int[65536]     @ 0        (256 KiB)
//   en2      : double[1024]   @ 262144   (8 KiB)
//   counts   : uint[1024]     @ 270336   (4 KiB)
//   loss_sum : double         @ 274432   (8 B)

#define VQ_M 65536
#define VQ_N 1024
#define VQ_E 256

// ---------------------------------------------------------------- kernel A
// per-code squared norms (fp64), + zero the ws accumulators (ws is poisoned).
__global__ __launch_bounds__(256) void vq_en2_init(
    const float* __restrict__ emb, double* __restrict__ en2,
    unsigned* __restrict__ counts, double* __restrict__ loss_sum) {
  const int tid  = threadIdx.x;
  const int lane = tid & 63;
  const int wave = tid >> 6;
  const int n    = blockIdx.x * 4 + wave;          // 256 blocks * 4 waves = 1024 codes
  const float4 e4 = reinterpret_cast<const float4*>(emb)[n * 64 + lane];
  double s = (double)e4.x * e4.x + (double)e4.y * e4.y +
             (double)e4.z * e4.z + (double)e4.w * e4.w;
#pragma unroll
  for (int m = 1; m < 64; m <<= 1) s += __shfl_xor(s, m, 64);
  if (lane == 0) en2[n] = s;
  if (blockIdx.x == 0) {
#pragma unroll
    for (int j = 0; j < 4; ++j) counts[tid + j * 256] = 0u;
    if (tid == 0) *loss_sum = 0.0;
  }
}

// ---------------------------------------------------------------- kernel B
// argmin_n ( ||e_n||^2 - 2 * x_m . e_n )  with fp64 accumulation.
// 1024 blocks x 256 threads. Block owns 64 rows; loops 16 N-tiles x 4 K-chunks.
// LDS tiles stored transposed [k][row] with pad 68 (16B-aligned rows -> b128).
__global__ __launch_bounds__(256) void vq_argmin(
    const float* __restrict__ X, const float* __restrict__ Emb,
    const double* __restrict__ en2, int* __restrict__ idxOut) {
  __shared__ float Xt[64 * 68];
  __shared__ float Et[64 * 68];
  const int tid = threadIdx.x;
  const int tx  = tid & 15;       // code sub-tile
  const int ty  = tid >> 4;       // row sub-tile
  const int m0  = blockIdx.x * 64;

  double bval[4];
  int    bidx[4];
#pragma unroll
  for (int i = 0; i < 4; ++i) { bval[i] = 1e300; bidx[i] = 0; }

  for (int nt = 0; nt < 16; ++nt) {
    double acc[4][4];
#pragma unroll
    for (int i = 0; i < 4; ++i)
#pragma unroll
      for (int j = 0; j < 4; ++j) acc[i][j] = 0.0;

    for (int kc = 0; kc < 4; ++kc) {
      __syncthreads();
      // stage X chunk [64 rows][64 k] and E chunk, transposed into LDS
#pragma unroll
      for (int i = 0; i < 4; ++i) {
        const int j   = tid + 256 * i;       // 0..1023
        const int row = j >> 4;              // 0..63
        const int kq  = j & 15;              // float4 index within chunk
        const float4 xv =
            reinterpret_cast<const float4*>(X)[(m0 + row) * 64 + kc * 16 + kq];
        const float4 ev =
            reinterpret_cast<const float4*>(Emb)[(nt * 64 + row) * 64 + kc * 16 + kq];
        Xt[(kq * 4 + 0) * 68 + row] = xv.x;
        Xt[(kq * 4 + 1) * 68 + row] = xv.y;
        Xt[(kq * 4 + 2) * 68 + row] = xv.z;
        Xt[(kq * 4 + 3) * 68 + row] = xv.w;
        Et[(kq * 4 + 0) * 68 + row] = ev.x;
        Et[(kq * 4 + 1) * 68 + row] = ev.y;
        Et[(kq * 4 + 2) * 68 + row] = ev.z;
        Et[(kq * 4 + 3) * 68 + row] = ev.w;
      }
      __syncthreads();
#pragma unroll 8
      for (int k = 0; k < 64; ++k) {
        const float4 a = *reinterpret_cast<const float4*>(&Xt[k * 68 + ty * 4]);
        const float4 b = *reinterpret_cast<const float4*>(&Et[k * 68 + tx * 4]);
        const double ad[4] = {a.x, a.y, a.z, a.w};
        const double bd[4] = {b.x, b.y, b.z, b.w};
#pragma unroll
        for (int i = 0; i < 4; ++i)
#pragma unroll
          for (int j = 0; j < 4; ++j) acc[i][j] += ad[i] * bd[j];
      }
    }
    // fold this N-tile into the running argmin (codes visited in ascending c)
#pragma unroll
    for (int j = 0; j < 4; ++j) {
      const int c = nt * 64 + tx * 4 + j;
      const double e2 = en2[c];
#pragma unroll
      for (int i = 0; i < 4; ++i) {
        const double d = e2 - 2.0 * acc[i][j];
        if (d < bval[i]) { bval[i] = d; bidx[i] = c; }
      }
    }
  }
  // reduce (val,idx) across the 16 tx-lanes; first-index tie-break
#pragma unroll
  for (int off = 1; off < 16; off <<= 1) {
#pragma unroll
    for (int i = 0; i < 4; ++i) {
      const double ov = __shfl_xor(bval[i], off, 64);
      const int    oi = __shfl_xor(bidx[i], off, 64);
      if (ov < bval[i] || (ov == bval[i] && oi < bidx[i])) {
        bval[i] = ov;
        bidx[i] = oi;
      }
    }
  }
  if (tx == 0) {
#pragma unroll
    for (int i = 0; i < 4; ++i) idxOut[m0 + ty * 4 + i] = bidx[i];
  }
}

// ---------------------------------------------------------------- kernel C
// gather + straight-through output + loss partial sum
__global__ __launch_bounds__(256) void vq_quant_loss(
    const float* __restrict__ X, const float* __restrict__ Emb,
    const int* __restrict__ idx, float* __restrict__ out,
    double* __restrict__ loss_sum) {
  const int F4_TOTAL = VQ_M * (VQ_E / 4);  // 4,194,304
  const int t = blockIdx.x * 256 + threadIdx.x;
  const int stride = gridDim.x * 256;
  double ls = 0.0;
  for (int i = t; i < F4_TOTAL; i += stride) {
    const int m  = i >> 6;    // 64 float4 per row
    const int k4 = i & 63;
    const int c  = idx[m];
    const float4 xv = reinterpret_cast<const float4*>(X)[i];
    const float4 ev = reinterpret_cast<const float4*>(Emb)[c * 64 + k4];
    const float dx = ev.x - xv.x;
    const float dy = ev.y - xv.y;
    const float dz = ev.z - xv.z;
    const float dw = ev.w - xv.w;
    float4 o;
    o.x = xv.x + dx;   // x + (q - x): straight-through numerics
    o.y = xv.y + dy;
    o.z = xv.z + dz;
    o.w = xv.w + dw;
    reinterpret_cast<float4*>(out)[i] = o;
    ls += (double)dx * dx + (double)dy * dy + (double)dz * dz + (double)dw * dw;
  }
#pragma unroll
  for (int m2 = 1; m2 < 64; m2 <<= 1) ls += __shfl_xor(ls, m2, 64);
  __shared__ double sh[4];
  const int lane = threadIdx.x & 63;
  const int w    = threadIdx.x >> 6;
  if (lane == 0) sh[w] = ls;
  __syncthreads();
  if (threadIdx.x == 0) atomicAdd(loss_sum, sh[0] + sh[1] + sh[2] + sh[3]);
}

// ---------------------------------------------------------------- kernel D
// code-usage histogram
__global__ __launch_bounds__(256) void vq_hist(const int* __restrict__ idx,
                                               unsigned* __restrict__ counts) {
  __shared__ unsigned h[VQ_N];
#pragma unroll
  for (int j = 0; j < 4; ++j) h[threadIdx.x + j * 256] = 0u;
  __syncthreads();
  const int stride = gridDim.x * 256;
  for (int i = blockIdx.x * 256 + threadIdx.x; i < VQ_M; i += stride)
    atomicAdd(&h[idx[i]], 1u);
  __syncthreads();
#pragma unroll
  for (int j = 0; j < 4; ++j) {
    const unsigned v = h[threadIdx.x + j * 256];
    if (v) atomicAdd(&counts[threadIdx.x + j * 256], v);
  }
}

// ---------------------------------------------------------------- kernel E
// loss = 1.25 * mean(diff^2); perplexity = exp(-sum p log(p+1e-10))
__global__ __launch_bounds__(1024) void vq_final(
    const unsigned* __restrict__ counts, const double* __restrict__ loss_sum,
    float* __restrict__ out) {
  const int tid = threadIdx.x;  // 1024 threads
  const double p = (double)counts[tid] * (1.0 / 65536.0);
  double term = -p * log(p + 1e-10);
#pragma unroll
  for (int m = 1; m < 64; m <<= 1) term += __shfl_xor(term, m, 64);
  __shared__ double sh[16];
  if ((tid & 63) == 0) sh[tid >> 6] = term;
  __syncthreads();
  if (tid == 0) {
    double H = 0.0;
#pragma unroll
    for (int i = 0; i < 16; ++i) H += sh[i];
    out[16777216] = (float)(1.25 * (*loss_sum) * (1.0 / 16777216.0));
    out[16777217] = (float)exp(H);
  }
}

// ---------------------------------------------------------------- launch
extern "C" void kernel_launch(void* const* d_in, const int* in_sizes, int n_in,
                              void* d_out, int out_size, void* d_ws, size_t ws_size,
                              hipStream_t stream) {
  const float* X   = (const float*)d_in[0];
  const float* Emb = (const float*)d_in[1];
  float* out = (float*)d_out;
  char* ws = (char*)d_ws;
  int*      idx      = (int*)(ws);
  double*   en2      = (double*)(ws + 262144);
  unsigned* counts   = (unsigned*)(ws + 270336);
  double*   loss_sum = (double*)(ws + 274432);

  vq_en2_init<<<256, 256, 0, stream>>>(Emb, en2, counts, loss_sum);
  vq_argmin<<<1024, 256, 0, stream>>>(X, Emb, en2, idx);
  vq_quant_loss<<<2048, 256, 0, stream>>>(X, Emb, idx, out, loss_sum);
  vq_hist<<<64, 256, 0, stream>>>(idx, counts);
  vq_final<<<1, 1024, 0, stream>>>(counts, loss_sum, out);
}

// Round 2
// 184.868 us; speedup vs baseline: 6.1662x; 6.1662x over previous
//
#include <hip/hip_runtime.h>

// VectorQuantizer: x [16,4096,256] f32, embedding [1024,256] f32
// outputs (concat): quantized_st [16,4096,256] f32, loss f32, perplexity f32
// M = 65536 rows, N = 1024 codes, E = 256 dims.
//
// ws layout:
//   idx      : int[65536]      @ 0       (256 KiB)
//   en2h     : float[1024]     @ 262144  (4 KiB)   holds -||e||^2 / 2
//   embB     : ushort[262144]  @ 266240  (512 KiB) bf16 embedding
//   counts   : uint[1024]      @ 790528  (4 KiB)
//   loss_sum : double          @ 794624  (8 B)

#define VQ_M 65536
#define VQ_N 1024
#define VQ_E 256

typedef __attribute__((ext_vector_type(8))) short bf16x8;
typedef __attribute__((ext_vector_type(4))) float f32x4;

// float -> bf16 round-to-nearest-even (bit trick; NaN irrelevant here)
__device__ __forceinline__ ushort f2b(float f) {
  unsigned u = __float_as_uint(f);
  unsigned r = (u + 0x7FFFu + ((u >> 16) & 1u)) >> 16;
  return (ushort)r;
}

// ---------------------------------------------------------------- kernel A
// en2h = -||e_n||^2/2 (fp64 reduce, fp32 store), emb -> bf16, zero accums.
__global__ __launch_bounds__(256) void vq_prep(
    const float* __restrict__ emb, float* __restrict__ en2h,
    ushort* __restrict__ embB, unsigned* __restrict__ counts,
    double* __restrict__ loss_sum) {
  const int tid  = threadIdx.x;
  const int lane = tid & 63;
  const int n    = blockIdx.x * 4 + (tid >> 6);   // 256 blocks * 4 waves
  const float4 e4 = reinterpret_cast<const float4*>(emb)[n * 64 + lane];
  double s = (double)e4.x * e4.x + (double)e4.y * e4.y +
             (double)e4.z * e4.z + (double)e4.w * e4.w;
#pragma unroll
  for (int m = 1; m < 64; m <<= 1) s += __shfl_xor(s, m, 64);
  if (lane == 0) en2h[n] = (float)(-0.5 * s);
  ushort4 b;
  b.x = f2b(e4.x); b.y = f2b(e4.y); b.z = f2b(e4.z); b.w = f2b(e4.w);
  reinterpret_cast<ushort4*>(embB)[n * 64 + lane] = b;
  if (blockIdx.x == 0) {
#pragma unroll
    for (int j = 0; j < 4; ++j) counts[tid + j * 256] = 0u;
    if (tid == 0) *loss_sum = 0.0;
  }
}

// ---------------------------------------------------------------- kernel B
// argmin via bf16 MFMA. D[code][xrow] = Emb . X^T, acc init = -||e||^2/2,
// so argmin(dist) == argmax(acc). X fragments live in registers (read once);
// Emb chunks [64 codes][256 k] bf16 stream through double-buffered LDS with
// XOR granule swizzle (g ^ (row&15)) for conflict-free ds_read_b128.
// Block = 4 waves, 128 xrows; wave = 32 xrows (fx=2) x 64 codes (cf=4)/chunk.
__global__ __launch_bounds__(256, 2) void vq_argmin_mfma(
    const float* __restrict__ X, const ushort* __restrict__ embB,
    const float* __restrict__ en2h, int* __restrict__ idxOut) {
  __shared__ ushort lds[2][64 * 256];   // 2 x 32 KiB
  const int tid = threadIdx.x;
  const int w   = tid >> 6;
  const int l   = tid & 63;
  const int lr  = l & 15;
  const int g4  = l >> 4;
  const int m0  = blockIdx.x * 128;

  // X fragments: row = m0 + w*32 + fx*16 + lr, k = kc*32 + g4*8 .. +8
  bf16x8 xf[2][8];
#pragma unroll
  for (int fx = 0; fx < 2; ++fx)
#pragma unroll
    for (int kc = 0; kc < 8; ++kc) {
      const float* p =
          X + (size_t)(m0 + w * 32 + fx * 16 + lr) * 256 + kc * 32 + g4 * 8;
      const float4 a = *reinterpret_cast<const float4*>(p);
      const float4 b = *reinterpret_cast<const float4*>(p + 4);
      bf16x8 v;
      v[0] = (short)f2b(a.x); v[1] = (short)f2b(a.y);
      v[2] = (short)f2b(a.z); v[3] = (short)f2b(a.w);
      v[4] = (short)f2b(b.x); v[5] = (short)f2b(b.y);
      v[6] = (short)f2b(b.z); v[7] = (short)f2b(b.w);
      xf[fx][kc] = v;
    }

  const float4* __restrict__ embB4 = reinterpret_cast<const float4*>(embB);

  // prologue: stage chunk 0
  {
    float4 s[8];
#pragma unroll
    for (int i = 0; i < 8; ++i) {
      const int gg = tid + 256 * i;            // granule 0..2047 (16B each)
      s[i] = embB4[(gg >> 5) * 32 + (gg & 31)];
    }
#pragma unroll
    for (int i = 0; i < 8; ++i) {
      const int gg = tid + 256 * i;
      const int row = gg >> 5, gc = gg & 31;
      reinterpret_cast<float4*>(lds[0])[row * 32 + (gc ^ (row & 15))] = s[i];
    }
  }
  __syncthreads();

  float bval[2] = {-3.4e38f, -3.4e38f};
  int   bidx[2] = {0, 0};

  for (int nt = 0; nt < 16; ++nt) {
    const int cur = nt & 1;
    // issue next-chunk global loads early (latency hides under MFMA)
    float4 s[8];
    if (nt < 15) {
#pragma unroll
      for (int i = 0; i < 8; ++i) {
        const int gg = tid + 256 * i;
        s[i] = embB4[((nt + 1) * 64 + (gg >> 5)) * 32 + (gg & 31)];
      }
    }
    // acc init = -||e||^2/2 for this chunk's codes
    f32x4 acc[4][2];
#pragma unroll
    for (int cf = 0; cf < 4; ++cf) {
      const f32x4 e2 =
          *reinterpret_cast<const f32x4*>(en2h + nt * 64 + cf * 16 + g4 * 4);
#pragma unroll
      for (int fx = 0; fx < 2; ++fx) acc[cf][fx] = e2;
    }
    // K loop: 8 chunks of 32
#pragma unroll
    for (int kc = 0; kc < 8; ++kc) {
      bf16x8 af[4];
#pragma unroll
      for (int cf = 0; cf < 4; ++cf)
        af[cf] = *reinterpret_cast<const bf16x8*>(
            &lds[cur][(cf * 16 + lr) * 256 + (((kc * 4 + g4) ^ lr) * 8)]);
#pragma unroll
      for (int cf = 0; cf < 4; ++cf)
#pragma unroll
        for (int fx = 0; fx < 2; ++fx)
          acc[cf][fx] = __builtin_amdgcn_mfma_f32_16x16x32_bf16(
              af[cf], xf[fx][kc], acc[cf][fx], 0, 0, 0);
    }
    // fold into running argmax (codes visited ascending; strict > keeps first)
#pragma unroll
    for (int cf = 0; cf < 4; ++cf)
#pragma unroll
      for (int fx = 0; fx < 2; ++fx)
#pragma unroll
        for (int q = 0; q < 4; ++q) {
          const float v = acc[cf][fx][q];
          const int code = nt * 64 + cf * 16 + g4 * 4 + q;
          if (v > bval[fx]) { bval[fx] = v; bidx[fx] = code; }
        }
    // write next chunk into the other buffer; one barrier per iter
    if (nt < 15) {
#pragma unroll
      for (int i = 0; i < 8; ++i) {
        const int gg = tid + 256 * i;
        const int row = gg >> 5, gc = gg & 31;
        reinterpret_cast<float4*>(lds[cur ^ 1])[row * 32 + (gc ^ (row & 15))] =
            s[i];
      }
      __syncthreads();
    }
  }

  // merge across the 4 lane-groups holding the same xrow (xor 16, 32)
#pragma unroll
  for (int off = 16; off <= 32; off <<= 1)
#pragma unroll
    for (int fx = 0; fx < 2; ++fx) {
      const float ov = __shfl_xor(bval[fx], off, 64);
      const int   oi = __shfl_xor(bidx[fx], off, 64);
      if (ov > bval[fx] || (ov == bval[fx] && oi < bidx[fx])) {
        bval[fx] = ov;
        bidx[fx] = oi;
      }
    }
  if (g4 == 0) {
#pragma unroll
    for (int fx = 0; fx < 2; ++fx)
      idxOut[m0 + w * 32 + fx * 16 + lr] = bidx[fx];
  }
}

// ---------------------------------------------------------------- kernel C
// gather + straight-through output + loss partial sum
__global__ __launch_bounds__(256) void vq_quant_loss(
    const float* __restrict__ X, const float* __restrict__ Emb,
    const int* __restrict__ idx, float* __restrict__ out,
    double* __restrict__ loss_sum) {
  const int F4_TOTAL = VQ_M * (VQ_E / 4);  // 4,194,304
  const int t = blockIdx.x * 256 + threadIdx.x;
  const int stride = gridDim.x * 256;
  double ls = 0.0;
  for (int i = t; i < F4_TOTAL; i += stride) {
    const int m  = i >> 6;    // 64 float4 per row
    const int k4 = i & 63;
    const int c  = idx[m];
    const float4 xv = reinterpret_cast<const float4*>(X)[i];
    const float4 ev = reinterpret_cast<const float4*>(Emb)[c * 64 + k4];
    const float dx = ev.x - xv.x;
    const float dy = ev.y - xv.y;
    const float dz = ev.z - xv.z;
    const float dw = ev.w - xv.w;
    float4 o;
    o.x = xv.x + dx;   // x + (q - x): straight-through numerics
    o.y = xv.y + dy;
    o.z = xv.z + dz;
    o.w = xv.w + dw;
    reinterpret_cast<float4*>(out)[i] = o;
    ls += (double)dx * dx + (double)dy * dy + (double)dz * dz + (double)dw * dw;
  }
#pragma unroll
  for (int m2 = 1; m2 < 64; m2 <<= 1) ls += __shfl_xor(ls, m2, 64);
  __shared__ double sh[4];
  const int lane = threadIdx.x & 63;
  const int wv   = threadIdx.x >> 6;
  if (lane == 0) sh[wv] = ls;
  __syncthreads();
  if (threadIdx.x == 0) atomicAdd(loss_sum, sh[0] + sh[1] + sh[2] + sh[3]);
}

// ---------------------------------------------------------------- kernel D
// code-usage histogram
__global__ __launch_bounds__(256) void vq_hist(const int* __restrict__ idx,
                                               unsigned* __restrict__ counts) {
  __shared__ unsigned h[VQ_N];
#pragma unroll
  for (int j = 0; j < 4; ++j) h[threadIdx.x + j * 256] = 0u;
  __syncthreads();
  const int stride = gridDim.x * 256;
  for (int i = blockIdx.x * 256 + threadIdx.x; i < VQ_M; i += stride)
    atomicAdd(&h[idx[i]], 1u);
  __syncthreads();
#pragma unroll
  for (int j = 0; j < 4; ++j) {
    const unsigned v = h[threadIdx.x + j * 256];
    if (v) atomicAdd(&counts[threadIdx.x + j * 256], v);
  }
}

// ---------------------------------------------------------------- kernel E
// loss = 1.25 * mean(diff^2); perplexity = exp(-sum p log(p+1e-10))
__global__ __launch_bounds__(1024) void vq_final(
    const unsigned* __restrict__ counts, const double* __restrict__ loss_sum,
    float* __restrict__ out) {
  const int tid = threadIdx.x;  // 1024 threads
  const double p = (double)counts[tid] * (1.0 / 65536.0);
  double term = -p * log(p + 1e-10);
#pragma unroll
  for (int m = 1; m < 64; m <<= 1) term += __shfl_xor(term, m, 64);
  __shared__ double sh[16];
  if ((tid & 63) == 0) sh[tid >> 6] = term;
  __syncthreads();
  if (tid == 0) {
    double H = 0.0;
#pragma unroll
    for (int i = 0; i < 16; ++i) H += sh[i];
    out[16777216] = (float)(1.25 * (*loss_sum) * (1.0 / 16777216.0));
    out[16777217] = (float)exp(H);
  }
}

// ---------------------------------------------------------------- launch
extern "C" void kernel_launch(void* const* d_in, const int* in_sizes, int n_in,
                              void* d_out, int out_size, void* d_ws, size_t ws_size,
                              hipStream_t stream) {
  const float* X   = (const float*)d_in[0];
  const float* Emb = (const float*)d_in[1];
  float* out = (float*)d_out;
  char* ws = (char*)d_ws;
  int*      idx      = (int*)(ws);
  float*    en2h     = (float*)(ws + 262144);
  ushort*   embB     = (ushort*)(ws + 266240);
  unsigned* counts   = (unsigned*)(ws + 790528);
  double*   loss_sum = (double*)(ws + 794624);

  vq_prep<<<256, 256, 0, stream>>>(Emb, en2h, embB, counts, loss_sum);
  vq_argmin_mfma<<<512, 256, 0, stream>>>(X, embB, en2h, idx);
  vq_quant_loss<<<2048, 256, 0, stream>>>(X, Emb, idx, out, loss_sum);
  vq_hist<<<64, 256, 0, stream>>>(idx, counts);
  vq_final<<<1, 1024, 0, stream>>>(counts, loss_sum, out);
}